// Round 3
// baseline (281.450 us; speedup 1.0000x reference)
//
#include <hip/hip_runtime.h>
#include <math.h>

typedef _Float16 f16;
typedef _Float16 half8 __attribute__((ext_vector_type(8)));
typedef float floatx4 __attribute__((ext_vector_type(4)));
typedef unsigned int u32;

#define B_   16
#define C_   128
#define O_   128
#define H_   56
#define W_   56
#define HW_  3136
#define NPIX 50176          // B*HW
#define NPC  50176.0f
#define NELEM 6422528
#define NW_  147456         // 9*128*128

// async 16B global->LDS copy (lane L lands at wave-uniform ldsbase + L*16)
typedef __attribute__((address_space(3))) u32 lds_u32;
typedef __attribute__((address_space(1))) u32 glb_u32;
__device__ __forceinline__ void async_copy16(const void* g, void* l) {
    __builtin_amdgcn_global_load_lds((const glb_u32*)g, (lds_u32*)l, 16, 0, 0);
}

// ---------------------------------------------------------------------------
// prep: w -> integer-valued fp16 weights rint(clip(w/alpha,-4,3)); alpha folded later
// ---------------------------------------------------------------------------
__global__ __launch_bounds__(256) void prep_kernel(
        const float* __restrict__ w1, const float* __restrict__ wa1,
        const float* __restrict__ w2, const float* __restrict__ wa2,
        f16* __restrict__ q1, f16* __restrict__ q2) {
    int idx = blockIdx.x * 256 + threadIdx.x;    // 0..2*NW_-1
    if (idx < NW_) {
        float a = wa1[idx >> 14];
        q1[idx] = (f16)rintf(fminf(fmaxf(w1[idx] / a, -4.f), 3.f));
    } else {
        int j = idx - NW_;
        float a = wa2[j >> 14];
        q2[j] = (f16)rintf(fminf(fmaxf(w2[j] / a, -4.f), 3.f));
    }
}

// ---------------------------------------------------------------------------
// transpose+split: x fp32 [B][C][HW] -> xh/xl fp16 [B*HW][C]; also zero aux
// ---------------------------------------------------------------------------
__global__ __launch_bounds__(256) void transpose_split_kernel(
        const float* __restrict__ x, f16* __restrict__ xh, f16* __restrict__ xl,
        float* __restrict__ aux) {
    __shared__ f16 hs[64][136];
    __shared__ f16 ls[64][136];
    const int t = threadIdx.x;
    const int blk = blockIdx.x;                 // 784 tiles of 64 px
    if (blk == 0) { for (int i = t; i < 640; i += 256) aux[i] = 0.f; }
    const int b = blk / 49;
    const int p0 = (blk - b * 49) * 64;
    #pragma unroll
    for (int i = 0; i < 8; ++i) {
        const int c = i * 16 + (t >> 4);
        const int px = (t & 15) * 4;
        const float4 v = *(const float4*)&x[((size_t)(b * C_ + c)) * HW_ + p0 + px];
        const float vv[4] = {v.x, v.y, v.z, v.w};
        #pragma unroll
        for (int j = 0; j < 4; ++j) {
            f16 h = (f16)vv[j];
            hs[px + j][c] = h;
            ls[px + j][c] = (f16)(vv[j] - (float)h);
        }
    }
    __syncthreads();
    const int px = t >> 2, seg = t & 3;
    const size_t ob = ((size_t)(b * HW_ + p0 + px)) * 128 + seg * 32;
    #pragma unroll
    for (int k = 0; k < 4; ++k) {
        *(half8*)(xh + ob + k * 8) = *(const half8*)&hs[px][seg * 32 + k * 8];
        *(half8*)(xl + ob + k * 8) = *(const half8*)&ls[px][seg * 32 + k * 8];
    }
}

// ---------------------------------------------------------------------------
// conv: 9-tap split conv, MFMA fp16 hi/lo.
// Block tile 64px x 128oc, grid 784 (= 3.06*256), LDS 48KB -> 3 blocks/CU.
// 4 waves, each 32px x 64oc. K chunks of 64 halves: (hi0,lo0,hi1,lo1).
// XOR swizzle on 16B groups; A staged double-buffered, B once per tap.
// ---------------------------------------------------------------------------
__global__ __launch_bounds__(256, 3) void conv_mfma_kernel(
        const f16* __restrict__ xh, const f16* __restrict__ xl,
        const f16* __restrict__ wq, const float* __restrict__ wav,
        const float* __restrict__ pav, const f16* __restrict__ zp,
        float* __restrict__ cout, float* __restrict__ stats) {
    __shared__ f16 As[2][64][64];    // 16 KB
    __shared__ f16 Bs[128][128];     // 32 KB
    const int t = threadIdx.x;
    const int lane = t & 63;
    const int wv = t >> 6;            // 0..3
    const int wm = wv & 1, wn = wv >> 1;
    const int tile = blockIdx.x;      // 784

    // ---- A staging precompute: 2 rows per thread ----
    int abase_[2], ah_[2], aw_[2], gbyteA[2];
    #pragma unroll
    for (int i = 0; i < 2; ++i) {
        const int r = i * 32 + wv * 8 + (lane >> 3);
        const int gp = tile * 64 + r;
        const int b = gp / HW_;
        const int p = gp - b * HW_;
        const int h = p / W_;
        const int w = p - h * W_;
        abase_[i] = b * HW_; ah_[i] = h; aw_[i] = w;
        gbyteA[i] = (((lane & 7) ^ (r & 7)) << 4);
    }
    // ---- B staging precompute: 8 issues per thread ----
    int boff[8];
    #pragma unroll
    for (int i = 0; i < 8; ++i) {
        const int r = wv * 32 + i * 4 + (lane >> 4);
        const int g = (lane & 15) ^ (r & 15);
        boff[i] = r * 256 + g * 16;
    }
    // ---- fragment read addresses ----
    const int ardbase = (wm * 32 + (lane & 15)) * 128;
    const char* Bbase = (const char*)&Bs[0][0] + (wn * 64 + (lane & 15)) * 256;
    int acol[2], bcol[2][2];
    #pragma unroll
    for (int ks = 0; ks < 2; ++ks) {
        acol[ks] = (((ks * 4 + (lane >> 4)) ^ (lane & 7)) << 4);
        bcol[0][ks] = (((ks * 4 + (lane >> 4)) ^ (lane & 15)) << 4);
        bcol[1][ks] = (((8 + ks * 4 + (lane >> 4)) ^ (lane & 15)) << 4);
    }

    floatx4 acc[2][4];
    floatx4 facc[2][4];
    const floatx4 z4 = {0.f, 0.f, 0.f, 0.f};
    #pragma unroll
    for (int mt = 0; mt < 2; ++mt)
        #pragma unroll
        for (int nt = 0; nt < 4; ++nt) facc[mt][nt] = z4;

    int aoff[2];
    const char* zpc = (const char*)zp;

    auto stageA = [&](int j, int bf) {
        const char* plane = (const char*)((j & 1) ? xl : xh);
        const int khb = (j >> 1) << 7;     // channel half within the 256B row
        #pragma unroll
        for (int i = 0; i < 2; ++i) {
            const char* g = (aoff[i] >= 0) ? plane + aoff[i] + khb + gbyteA[i]
                                           : zpc + gbyteA[i];
            async_copy16(g, (void*)&As[bf][i * 32 + wv * 8][0]);
        }
    };

    for (int tap = 0; tap < 9; ++tap) {
        const int di = tap - (tap / 3) * 3 - 1;   // h shift
        const int dj = tap / 3 - 1;               // w shift
        const float pak = pav[tap];
        const float s1 = wav[tap] / pak;

        #pragma unroll
        for (int i = 0; i < 2; ++i) {
            const int hp = ah_[i] + di, wp = aw_[i] + dj;
            const bool v = ((unsigned)hp < (unsigned)H_) && ((unsigned)wp < (unsigned)W_);
            aoff[i] = v ? ((abase_[i] + hp * W_ + wp) << 8) : -1;
        }
        #pragma unroll
        for (int mt = 0; mt < 2; ++mt)
            #pragma unroll
            for (int nt = 0; nt < 4; ++nt) acc[mt][nt] = z4;

        // stage B (full tap) + A chunk 0
        const char* wt = (const char*)wq + (tap << 15);
        #pragma unroll
        for (int i = 0; i < 8; ++i)
            async_copy16(wt + boff[i], (void*)&Bs[wv * 32 + i * 4][0]);
        stageA(0, 0);
        __syncthreads();

        for (int j = 0; j < 4; ++j) {
            if (j < 3) stageA(j + 1, (j + 1) & 1);
            const char* Ab = (const char*)&As[j & 1][0][0] + ardbase;
            const int kh = j >> 1;
            #pragma unroll
            for (int ks = 0; ks < 2; ++ks) {
                half8 af[2], bf4[4];
                #pragma unroll
                for (int mt = 0; mt < 2; ++mt)
                    af[mt] = *(const half8*)(Ab + mt * 2048 + acol[ks]);
                #pragma unroll
                for (int nt = 0; nt < 4; ++nt)
                    bf4[nt] = *(const half8*)(Bbase + nt * 4096 + bcol[kh][ks]);
                #pragma unroll
                for (int nt = 0; nt < 4; ++nt)
                    #pragma unroll
                    for (int mt = 0; mt < 2; ++mt)
                        acc[mt][nt] = __builtin_amdgcn_mfma_f32_16x16x32_f16(
                            af[mt], bf4[nt], acc[mt][nt], 0, 0, 0);
            }
            __syncthreads();
        }

        // 8-bit LSQ quantize partial sum, accumulate
        #pragma unroll
        for (int mt = 0; mt < 2; ++mt)
            #pragma unroll
            for (int nt = 0; nt < 4; ++nt) {
                #pragma unroll
                for (int e = 0; e < 4; ++e) {
                    float q = rintf(fminf(fmaxf(acc[mt][nt][e] * s1, -128.f), 127.f));
                    facc[mt][nt][e] = fmaf(q, pak, facc[mt][nt][e]);
                }
            }
    }

    // ---- epilogue: write cout [gp][oc] fp32 ----
    const int gp0 = tile * 64 + wm * 32;
    const int ocb = wn * 64 + (lane & 15);
    #pragma unroll
    for (int mt = 0; mt < 2; ++mt)
        #pragma unroll
        for (int e = 0; e < 4; ++e) {
            const int gp = gp0 + mt * 16 + ((lane >> 4) << 2) + e;
            float* rp = cout + (size_t)gp * 128 + ocb;
            rp[0]  = facc[mt][0][e];
            rp[16] = facc[mt][1][e];
            rp[32] = facc[mt][2][e];
            rp[48] = facc[mt][3][e];
        }

    // ---- fused BN stats: per-oc sum/sumsq over this block's 64 px ----
    float* red = (float*)&As[0][0][0];   // 1024 floats scratch
    float sv[4], qv[4];
    #pragma unroll
    for (int nt = 0; nt < 4; ++nt) {
        float s = 0.f, q = 0.f;
        #pragma unroll
        for (int mt = 0; mt < 2; ++mt)
            #pragma unroll
            for (int e = 0; e < 4; ++e) {
                const float v = facc[mt][nt][e];
                s += v; q = fmaf(v, v, q);
            }
        s += __shfl_xor(s, 16, 64); s += __shfl_xor(s, 32, 64);
        q += __shfl_xor(q, 16, 64); q += __shfl_xor(q, 32, 64);
        sv[nt] = s; qv[nt] = q;
    }
    if (lane < 16) {
        #pragma unroll
        for (int nt = 0; nt < 4; ++nt) {
            const int oc = wn * 64 + nt * 16 + lane;
            red[oc * 2 + wm] = sv[nt];
            red[512 + oc * 2 + wm] = qv[nt];
        }
    }
    __syncthreads();
    if (t < 128) {
        atomicAdd(&stats[t],       red[2 * t] + red[2 * t + 1]);
        atomicAdd(&stats[128 + t], red[512 + 2 * t] + red[512 + 2 * t + 1]);
    }
}

// ---------------------------------------------------------------------------
// bn+relu+split: cout fp32 [gp][oc] -> xh/xl fp16 (conv2 input); coef from stats
// ---------------------------------------------------------------------------
__global__ __launch_bounds__(256) void bn_split_kernel(
        const float* __restrict__ cin, const float* __restrict__ stats,
        const float* __restrict__ g, const float* __restrict__ bb,
        f16* __restrict__ xh, f16* __restrict__ xl) {
    __shared__ float sc_s[128], sh_s[128];
    const int t = threadIdx.x;
    if (t < 128) {
        const float m = stats[t] * (1.f / NPC);
        const float var = stats[128 + t] * (1.f / NPC) - m * m;
        const float inv = 1.f / sqrtf(var + 1e-5f);
        const float sc = g[t] * inv;
        sc_s[t] = sc;
        sh_s[t] = bb[t] - m * sc;
    }
    __syncthreads();
    const int idx = blockIdx.x * 256 + t;    // < 802816
    const size_t base = (size_t)idx * 8;
    const int oc0 = (idx & 15) * 8;
    const float4 va = *(const float4*)(cin + base);
    const float4 vb = *(const float4*)(cin + base + 4);
    const float4 s0 = *(const float4*)(sc_s + oc0);
    const float4 s1 = *(const float4*)(sc_s + oc0 + 4);
    const float4 h0 = *(const float4*)(sh_s + oc0);
    const float4 h1 = *(const float4*)(sh_s + oc0 + 4);
    float y[8];
    y[0] = fmaxf(fmaf(va.x, s0.x, h0.x), 0.f);
    y[1] = fmaxf(fmaf(va.y, s0.y, h0.y), 0.f);
    y[2] = fmaxf(fmaf(va.z, s0.z, h0.z), 0.f);
    y[3] = fmaxf(fmaf(va.w, s0.w, h0.w), 0.f);
    y[4] = fmaxf(fmaf(vb.x, s1.x, h1.x), 0.f);
    y[5] = fmaxf(fmaf(vb.y, s1.y, h1.y), 0.f);
    y[6] = fmaxf(fmaf(vb.z, s1.z, h1.z), 0.f);
    y[7] = fmaxf(fmaf(vb.w, s1.w, h1.w), 0.f);
    half8 hv, lv;
    #pragma unroll
    for (int j = 0; j < 8; ++j) {
        f16 hh = (f16)y[j];
        hv[j] = hh;
        lv[j] = (f16)(y[j] - (float)hh);
    }
    *(half8*)(xh + base) = hv;
    *(half8*)(xl + base) = lv;
}

// ---------------------------------------------------------------------------
// final: bn2 + residual + relu, [gp][oc] -> [b][c][p] transpose; coef from stats
// ---------------------------------------------------------------------------
__global__ __launch_bounds__(256) void final_kernel(
        const float* __restrict__ cin, const float* __restrict__ stats,
        const float* __restrict__ g, const float* __restrict__ bb,
        const float* __restrict__ resid, float* __restrict__ out) {
    __shared__ float ts[128][68];
    __shared__ float sc_s[128], sh_s[128];
    const int t = threadIdx.x;
    if (t < 128) {
        const float m = stats[t] * (1.f / NPC);
        const float var = stats[128 + t] * (1.f / NPC) - m * m;
        const float inv = 1.f / sqrtf(var + 1e-5f);
        const float sc = g[t] * inv;
        sc_s[t] = sc;
        sh_s[t] = bb[t] - m * sc;
    }
    __syncthreads();
    const int blk = blockIdx.x;                 // 784
    const int b = blk / 49;
    const int p0 = (blk - b * 49) * 64;
    #pragma unroll
    for (int i = 0; i < 8; ++i) {
        const int lin = i * 256 + t;            // 0..2047
        const int px = lin >> 5;
        const int oc = (lin & 31) * 4;
        const float4 v = *(const float4*)&cin[((size_t)(b * HW_ + p0 + px)) * 128 + oc];
        const float4 sc = *(const float4*)&sc_s[oc];
        const float4 sh = *(const float4*)&sh_s[oc];
        ts[oc + 0][px] = fmaf(v.x, sc.x, sh.x);
        ts[oc + 1][px] = fmaf(v.y, sc.y, sh.y);
        ts[oc + 2][px] = fmaf(v.z, sc.z, sh.z);
        ts[oc + 3][px] = fmaf(v.w, sc.w, sh.w);
    }
    __syncthreads();
    #pragma unroll
    for (int i = 0; i < 2; ++i) {
        const int c = i * 64 + (t >> 2);
        const int px = (t & 3) * 16;
        const size_t go = ((size_t)(b * C_ + c)) * HW_ + p0 + px;
        #pragma unroll
        for (int k = 0; k < 4; ++k) {
            float4 v = *(const float4*)&ts[c][px + k * 4];
            const float4 r = *(const float4*)&resid[go + k * 4];
            v.x = fmaxf(v.x + r.x, 0.f);
            v.y = fmaxf(v.y + r.y, 0.f);
            v.z = fmaxf(v.z + r.z, 0.f);
            v.w = fmaxf(v.w + r.w, 0.f);
            *(float4*)&out[go + k * 4] = v;
        }
    }
}

// ---------------------------------------------------------------------------
extern "C" void kernel_launch(void* const* d_in, const int* in_sizes, int n_in,
                              void* d_out, int out_size, void* d_ws, size_t ws_size,
                              hipStream_t stream) {
    const float* x   = (const float*)d_in[0];
    const float* w1  = (const float*)d_in[1];
    const float* wa1 = (const float*)d_in[2];
    const float* pa1 = (const float*)d_in[3];
    const float* g1  = (const float*)d_in[4];
    const float* b1  = (const float*)d_in[5];
    const float* w2  = (const float*)d_in[6];
    const float* wa2 = (const float*)d_in[7];
    const float* pa2 = (const float*)d_in[8];
    const float* g2  = (const float*)d_in[9];
    const float* b2  = (const float*)d_in[10];
    float* out = (float*)d_out;

    // ws layout (bytes): xh 12845056 | xl 12845056 | wq1 294912 | wq2 294912 |
    //                    cbuf 25690112 | aux 2560
    char* ws = (char*)d_ws;
    f16* xh  = (f16*)ws;
    f16* xl  = (f16*)(ws + 12845056);
    f16* wq1 = (f16*)(ws + 25690112);
    f16* wq2 = (f16*)(ws + 25690112 + 294912);
    float* cbuf = (float*)(ws + 25690112 + 2 * 294912);
    float* aux  = (float*)(ws + 25690112 + 2 * 294912 + 25690112);
    // aux floats: [0,256) stats1 | [256,512) stats2 | [512,640) zero page
    float* stats1 = aux;
    float* stats2 = aux + 256;
    const f16* zp = (const f16*)(aux + 512);

    hipLaunchKernelGGL(prep_kernel, dim3(1152), dim3(256), 0, stream,
                       w1, wa1, w2, wa2, wq1, wq2);
    hipLaunchKernelGGL(transpose_split_kernel, dim3(784), dim3(256), 0, stream,
                       x, xh, xl, aux);
    hipLaunchKernelGGL(conv_mfma_kernel, dim3(784), dim3(256), 0, stream,
                       xh, xl, wq1, wa1, pa1, zp, cbuf, stats1);
    hipLaunchKernelGGL(bn_split_kernel, dim3(3136), dim3(256), 0, stream,
                       cbuf, stats1, g1, b1, xh, xl);
    hipLaunchKernelGGL(conv_mfma_kernel, dim3(784), dim3(256), 0, stream,
                       xh, xl, wq2, wa2, pa2, zp, cbuf, stats2);
    hipLaunchKernelGGL(final_kernel, dim3(784), dim3(256), 0, stream,
                       cbuf, stats2, g2, b2, x, out);
}

// Round 4
// 233.247 us; speedup vs baseline: 1.2067x; 1.2067x over previous
//
#include <hip/hip_runtime.h>
#include <math.h>

typedef _Float16 f16;
typedef _Float16 half8 __attribute__((ext_vector_type(8)));
typedef float floatx16 __attribute__((ext_vector_type(16)));

#define HW_     3136
#define NPC     50176.0f
#define PB      3364            // 58*58 padded pixels per image
#define PPLANE  53824           // 16 images * PB (chunks per k2-plane)
#define ASTRIDE ((size_t)2 * PPLANE * 16)   // bytes between s-steps (k2 += 2)

// LDS rotation swizzle: conflict-free for both (c fixed, px varies) and
// (px fixed, c varies with stride 4) access patterns.
#define SW(c, px) (((px) + ((c) >> 2) + ((c) & 3) * 8) & 63)

// ---------------------------------------------------------------------------
// prep: quantize weights to integer-valued fp16 and pack MFMA-fragment-major:
// W2[(tap*16 + k2)*128 + oc] = 8 f16 chunk of channels k2*8..k2*8+7
// ---------------------------------------------------------------------------
__global__ __launch_bounds__(256) void prep_kernel(
        const float* __restrict__ w1, const float* __restrict__ wa1,
        const float* __restrict__ w2, const float* __restrict__ wa2,
        f16* __restrict__ W2a, f16* __restrict__ W2b) {
    const int idx = blockIdx.x * 256 + threadIdx.x;    // 0..36863
    const float* w;
    const float* wa;
    f16* o;
    int m;
    if (idx < 18432) { w = w1; wa = wa1; o = W2a; m = idx; }
    else             { w = w2; wa = wa2; o = W2b; m = idx - 18432; }
    const int tap = m >> 11;
    const int r = m & 2047;
    const int k2 = r >> 7;
    const int oc = r & 127;
    const float a = wa[tap];
    const float* src = w + ((size_t)(tap * 128 + oc) * 128 + k2 * 8);
    half8 hv;
#pragma unroll
    for (int j = 0; j < 8; ++j)
        hv[j] = (f16)rintf(fminf(fmaxf(src[j] / a, -4.f), 3.f));
    *(half8*)(o + (size_t)m * 8) = hv;
}

// ---------------------------------------------------------------------------
// pad: zero the spatial border chunks of X2 (all 32 k2-planes, 16 images)
// ---------------------------------------------------------------------------
__global__ __launch_bounds__(256) void pad_kernel(char* __restrict__ X2) {
    const int idx = blockIdx.x * 256 + threadIdx.x;    // 116736 = 32*16*228
    const int k2 = idx / 3648;
    const int r = idx - k2 * 3648;
    const int b = r / 228;
    const int j = r - b * 228;
    int h, w;
    if (j < 58)        { h = 0;  w = j; }
    else if (j < 116)  { h = 57; w = j - 58; }
    else { const int k = j - 116; h = 1 + (k >> 1); w = (k & 1) * 57; }
    const size_t chunk = (size_t)k2 * PPLANE + (size_t)b * PB + h * 58 + w;
    float4 z = {0.f, 0.f, 0.f, 0.f};
    *(float4*)(X2 + chunk * 16) = z;
}

// ---------------------------------------------------------------------------
// pack: x fp32 [b][c][hw] -> X2 hi/lo fp16 chunks [k2][b][hp][wp]
// ---------------------------------------------------------------------------
__global__ __launch_bounds__(256) void pack_kernel(
        const float* __restrict__ x, char* __restrict__ X2,
        float* __restrict__ stats) {
    __shared__ float xs[8192];
    const int t = threadIdx.x;
    const int blk = blockIdx.x;                  // 784
    if (blk == 0 && t < 512) stats[t] = 0.f;     // zero stats1+stats2
    const int b = blk / 49;
    const int p0 = (blk - b * 49) * 64;
    const int lane = t & 63, wq = t >> 6;
#pragma unroll
    for (int i = 0; i < 32; ++i) {
        const int c = i * 4 + wq;
        const float v = x[(size_t)(b * 128 + c) * HW_ + p0 + lane];
        xs[c * 64 + SW(c, lane)] = v;
    }
    __syncthreads();
    const int p = p0 + lane;
    const int h = p / 56;
    const int w = p - h * 56;
    const size_t pp = (size_t)b * PB + (h + 1) * 58 + (w + 1);
#pragma unroll
    for (int s = 0; s < 4; ++s) {
        const int cg = s * 4 + wq;               // 0..15
        half8 hv, lv;
#pragma unroll
        for (int j = 0; j < 8; ++j) {
            const int c = cg * 8 + j;
            const float v = xs[c * 64 + SW(c, lane)];
            const f16 hh = (f16)v;
            hv[j] = hh;
            lv[j] = (f16)(v - (float)hh);
        }
        *(half8*)(X2 + ((size_t)cg * PPLANE + pp) * 16) = hv;
        *(half8*)(X2 + ((size_t)(cg + 16) * PPLANE + pp) * 16) = lv;
    }
}

// ---------------------------------------------------------------------------
// conv: barrier-free MFMA split-conv. Block = 128px x 128oc, 4 waves 64x64.
// A: direct global loads from packed-padded X2 (rotating 4-deep prefetch).
// B: 16 register fragments per tap from packed W2. No LDS in main loop.
// ---------------------------------------------------------------------------
__global__ __launch_bounds__(256, 2) void conv_kernel(
        const char* __restrict__ X2, const char* __restrict__ W2,
        const float* __restrict__ wav, const float* __restrict__ pav,
        float* __restrict__ cbuf, float* __restrict__ stats) {
    __shared__ float red[512];
    const int t = threadIdx.x;
    const int lane = t & 63;
    const int wv = t >> 6;
    const int wm = wv & 1, wn = wv >> 1;
    const int tile = (blockIdx.x & 7) * 49 + (blockIdx.x >> 3);  // XCD swizzle
    const int kh = lane >> 5;
    const int ln = lane & 31;

    int ppad[2];
#pragma unroll
    for (int mt = 0; mt < 2; ++mt) {
        const int gp = tile * 128 + wm * 64 + mt * 32 + ln;
        const int b = gp / HW_;
        const int p = gp - b * HW_;
        const int h = p / 56;
        const int w = p - h * 56;
        ppad[mt] = b * PB + (h + 1) * 58 + (w + 1);
    }
    int bb2[2];
#pragma unroll
    for (int nt = 0; nt < 2; ++nt)
        bb2[nt] = (kh * 128 + wn * 64 + nt * 32 + ln) * 16;

    floatx16 facc[2][2];
#pragma unroll
    for (int mt = 0; mt < 2; ++mt)
#pragma unroll
        for (int nt = 0; nt < 2; ++nt)
#pragma unroll
            for (int r = 0; r < 16; ++r) facc[mt][nt][r] = 0.f;

    for (int tap = 0; tap < 9; ++tap) {
        const int di = tap - (tap / 3) * 3 - 1;
        const int dj = tap / 3 - 1;
        const float pak = pav[tap];
        const float s1 = wav[tap] / pak;
        const int doff = di * 58 + dj;

        // B fragments for this tap (reused by hi and lo halves)
        const char* wt = W2 + tap * 32768;
        half8 bfr[2][8];
#pragma unroll
        for (int nt = 0; nt < 2; ++nt)
#pragma unroll
            for (int kf = 0; kf < 8; ++kf)
                bfr[nt][kf] = *(const half8*)(wt + bb2[nt] + kf * 4096);

        size_t aoff[2];
#pragma unroll
        for (int mt = 0; mt < 2; ++mt)
            aoff[mt] = ((size_t)(ppad[mt] + doff) + (size_t)kh * PPLANE) * 16;

        half8 afr[2][4];
#pragma unroll
        for (int s0 = 0; s0 < 4; ++s0)
#pragma unroll
            for (int mt = 0; mt < 2; ++mt)
                afr[mt][s0] = *(const half8*)(X2 + aoff[mt] + (size_t)s0 * ASTRIDE);

        floatx16 acc[2][2];
#pragma unroll
        for (int mt = 0; mt < 2; ++mt)
#pragma unroll
            for (int nt = 0; nt < 2; ++nt)
#pragma unroll
                for (int r = 0; r < 16; ++r) acc[mt][nt][r] = 0.f;

#pragma unroll
        for (int s = 0; s < 16; ++s) {
#pragma unroll
            for (int nt = 0; nt < 2; ++nt)
#pragma unroll
                for (int mt = 0; mt < 2; ++mt)
                    acc[mt][nt] = __builtin_amdgcn_mfma_f32_32x32x16_f16(
                        afr[mt][s & 3], bfr[nt][s & 7], acc[mt][nt], 0, 0, 0);
            if (s < 12) {
#pragma unroll
                for (int mt = 0; mt < 2; ++mt)
                    afr[mt][s & 3] =
                        *(const half8*)(X2 + aoff[mt] + (size_t)(s + 4) * ASTRIDE);
            }
        }

        // per-tap 8-bit LSQ quantize of the partial sum, accumulate
#pragma unroll
        for (int mt = 0; mt < 2; ++mt)
#pragma unroll
            for (int nt = 0; nt < 2; ++nt)
#pragma unroll
                for (int r = 0; r < 16; ++r) {
                    const float q =
                        rintf(fminf(fmaxf(acc[mt][nt][r] * s1, -128.f), 127.f));
                    facc[mt][nt][r] = fmaf(q, pak, facc[mt][nt][r]);
                }
    }

    // epilogue: cbuf [gp][oc] fp32   (32x32 C/D: row=(r&3)+8*(r>>2)+4*kh, col=ln)
    const int gpb = tile * 128 + wm * 64;
    const int ocb = wn * 64 + ln;
#pragma unroll
    for (int mt = 0; mt < 2; ++mt)
#pragma unroll
        for (int r = 0; r < 16; ++r) {
            const int row = (r & 3) + 8 * (r >> 2) + 4 * kh;
            const int gp = gpb + mt * 32 + row;
            float* rp = cbuf + (size_t)gp * 128 + ocb;
            rp[0]  = facc[mt][0][r];
            rp[32] = facc[mt][1][r];
        }

    // fused BN stats
    float sv[2], qv[2];
#pragma unroll
    for (int nt = 0; nt < 2; ++nt) {
        float s = 0.f, q = 0.f;
#pragma unroll
        for (int mt = 0; mt < 2; ++mt)
#pragma unroll
            for (int r = 0; r < 16; ++r) {
                const float v = facc[mt][nt][r];
                s += v;
                q = fmaf(v, v, q);
            }
        s += __shfl_xor(s, 32, 64);
        q += __shfl_xor(q, 32, 64);
        sv[nt] = s; qv[nt] = q;
    }
    if (lane < 32) {
#pragma unroll
        for (int nt = 0; nt < 2; ++nt) {
            const int oc = wn * 64 + nt * 32 + lane;
            red[oc * 2 + wm] = sv[nt];
            red[256 + oc * 2 + wm] = qv[nt];
        }
    }
    __syncthreads();
    if (t < 128) {
        atomicAdd(&stats[t],       red[2 * t] + red[2 * t + 1]);
        atomicAdd(&stats[128 + t], red[256 + 2 * t] + red[256 + 2 * t + 1]);
    }
}

// ---------------------------------------------------------------------------
// bn_split: cbuf fp32 [gp][oc] -> bn+relu -> X2 hi/lo packed (conv2 input)
// ---------------------------------------------------------------------------
__global__ __launch_bounds__(256) void bn_split_kernel(
        const float* __restrict__ cbuf, const float* __restrict__ stats,
        const float* __restrict__ g, const float* __restrict__ bb,
        char* __restrict__ X2) {
    __shared__ float xs[8192];
    __shared__ float scs[128], shs[128];
    const int t = threadIdx.x;
    if (t < 128) {
        const float m = stats[t] * (1.f / NPC);
        const float var = stats[128 + t] * (1.f / NPC) - m * m;
        const float inv = 1.f / sqrtf(var + 1e-5f);
        const float sc = g[t] * inv;
        scs[t] = sc;
        shs[t] = bb[t] - m * sc;
    }
    __syncthreads();
    const int blk = blockIdx.x;                  // 784
#pragma unroll
    for (int i = 0; i < 8; ++i) {
        const int idx = i * 256 + t;
        const int px = idx >> 5;
        const int q = idx & 31;
        const float4 v = *(const float4*)&cbuf[(size_t)(blk * 64 + px) * 128 + q * 4];
        const float vv[4] = {v.x, v.y, v.z, v.w};
#pragma unroll
        for (int j = 0; j < 4; ++j) {
            const int c = q * 4 + j;
            const float y = fmaxf(fmaf(vv[j], scs[c], shs[c]), 0.f);
            xs[c * 64 + SW(c, px)] = y;
        }
    }
    __syncthreads();
    const int b = blk / 49;
    const int p0 = (blk - b * 49) * 64;
    const int lane = t & 63, wq = t >> 6;
    const int p = p0 + lane;
    const int h = p / 56;
    const int w = p - h * 56;
    const size_t pp = (size_t)b * PB + (h + 1) * 58 + (w + 1);
#pragma unroll
    for (int s = 0; s < 4; ++s) {
        const int cg = s * 4 + wq;
        half8 hv, lv;
#pragma unroll
        for (int j = 0; j < 8; ++j) {
            const int c = cg * 8 + j;
            const float v = xs[c * 64 + SW(c, lane)];
            const f16 hh = (f16)v;
            hv[j] = hh;
            lv[j] = (f16)(v - (float)hh);
        }
        *(half8*)(X2 + ((size_t)cg * PPLANE + pp) * 16) = hv;
        *(half8*)(X2 + ((size_t)(cg + 16) * PPLANE + pp) * 16) = lv;
    }
}

// ---------------------------------------------------------------------------
// final: bn2 + residual add + relu, [gp][oc] -> [b][c][hw]
// ---------------------------------------------------------------------------
__global__ __launch_bounds__(256) void final_kernel(
        const float* __restrict__ cbuf, const float* __restrict__ stats,
        const float* __restrict__ g, const float* __restrict__ bb,
        const float* __restrict__ resid, float* __restrict__ out) {
    __shared__ float xs[8192];
    __shared__ float scs[128], shs[128];
    const int t = threadIdx.x;
    if (t < 128) {
        const float m = stats[t] * (1.f / NPC);
        const float var = stats[128 + t] * (1.f / NPC) - m * m;
        const float inv = 1.f / sqrtf(var + 1e-5f);
        const float sc = g[t] * inv;
        scs[t] = sc;
        shs[t] = bb[t] - m * sc;
    }
    __syncthreads();
    const int blk = blockIdx.x;                  // 784
#pragma unroll
    for (int i = 0; i < 8; ++i) {
        const int idx = i * 256 + t;
        const int px = idx >> 5;
        const int q = idx & 31;
        const float4 v = *(const float4*)&cbuf[(size_t)(blk * 64 + px) * 128 + q * 4];
        const float vv[4] = {v.x, v.y, v.z, v.w};
#pragma unroll
        for (int j = 0; j < 4; ++j) {
            const int c = q * 4 + j;
            xs[c * 64 + SW(c, px)] = fmaf(vv[j], scs[c], shs[c]);
        }
    }
    __syncthreads();
    const int b = blk / 49;
    const int p0 = (blk - b * 49) * 64;
    const int lane = t & 63, wq = t >> 6;
#pragma unroll
    for (int i = 0; i < 32; ++i) {
        const int c = i * 4 + wq;
        const float v = xs[c * 64 + SW(c, lane)];
        const size_t gi = (size_t)(b * 128 + c) * HW_ + p0 + lane;
        out[gi] = fmaxf(v + resid[gi], 0.f);
    }
}

// ---------------------------------------------------------------------------
extern "C" void kernel_launch(void* const* d_in, const int* in_sizes, int n_in,
                              void* d_out, int out_size, void* d_ws, size_t ws_size,
                              hipStream_t stream) {
    const float* x   = (const float*)d_in[0];
    const float* w1  = (const float*)d_in[1];
    const float* wa1 = (const float*)d_in[2];
    const float* pa1 = (const float*)d_in[3];
    const float* g1  = (const float*)d_in[4];
    const float* b1  = (const float*)d_in[5];
    const float* w2  = (const float*)d_in[6];
    const float* wa2 = (const float*)d_in[7];
    const float* pa2 = (const float*)d_in[8];
    const float* g2  = (const float*)d_in[9];
    const float* b2  = (const float*)d_in[10];
    float* out = (float*)d_out;

    // ws layout (bytes):
    //   X2    @ 0          : 27,557,888  (32 planes * 53824 chunks * 16 B)
    //   cbuf  @ 27,557,888 : 25,690,112
    //   W2a   @ 53,248,000 :    294,912
    //   W2b   @ 53,542,912 :    294,912
    //   stats @ 53,837,824 :      2,048  (stats1 256 f + stats2 256 f)
    char* ws = (char*)d_ws;
    char*  X2    = ws;
    float* cbuf  = (float*)(ws + 27557888);
    f16*   W2a   = (f16*)(ws + 53248000);
    f16*   W2b   = (f16*)(ws + 53542912);
    float* stats = (float*)(ws + 53837824);
    float* stats1 = stats;
    float* stats2 = stats + 256;

    hipLaunchKernelGGL(prep_kernel, dim3(144), dim3(256), 0, stream,
                       w1, wa1, w2, wa2, W2a, W2b);
    hipLaunchKernelGGL(pad_kernel, dim3(456), dim3(256), 0, stream, X2);
    hipLaunchKernelGGL(pack_kernel, dim3(784), dim3(256), 0, stream,
                       x, X2, stats);
    hipLaunchKernelGGL(conv_kernel, dim3(392), dim3(256), 0, stream,
                       X2, (const char*)W2a, wa1, pa1, cbuf, stats1);
    hipLaunchKernelGGL(bn_split_kernel, dim3(784), dim3(256), 0, stream,
                       cbuf, stats1, g1, b1, X2);
    hipLaunchKernelGGL(conv_kernel, dim3(392), dim3(256), 0, stream,
                       X2, (const char*)W2b, wa2, pa2, cbuf, stats2);
    hipLaunchKernelGGL(final_kernel, dim3(784), dim3(256), 0, stream,
                       cbuf, stats2, g2, b2, x, out);
}